// Round 1
// baseline (508.809 us; speedup 1.0000x reference)
//
#include <hip/hip_runtime.h>
#include <hip/hip_bf16.h>
#include <stdint.h>

#define BATCH 8
#define NPOS 4096   // H*W = 64*64

typedef __attribute__((ext_vector_type(4))) float f32x4;
typedef __attribute__((ext_vector_type(8))) short bf16x8;

__device__ __forceinline__ unsigned short bf_rne(float f) {
    unsigned u = __float_as_uint(f);
    u += 0x7fffu + ((u >> 16) & 1u);
    return (unsigned short)(u >> 16);
}
__device__ __forceinline__ float bf_f(unsigned short s) {
    return __uint_as_float(((unsigned)s) << 16);
}

// ---------------------------------------------------------------------------
// Kernel 1: both 1x1 convs. Each block: one batch b, 64 positions, 64 threads.
// Thread t owns position n = nb*64 + t, computes all 64 output channels.
// Writes:
//   KThi/KTlo [B][N][64] bf16 (A = low conv, transposed)   -> K operand (hi/lo split)
//   QThi/QTlo [B][N][64] bf16 (Bf = high conv, transposed) -> Q operand (hi/lo split)
//   Vc        [B][64][N] bf16 (Bf, channel-major)          -> V operand
//   R32       [B][64][N] f32  (Bf, channel-major)          -> residual
// ---------------------------------------------------------------------------
__global__ __launch_bounds__(64)
void conv_prep(const float* __restrict__ xlow, const float* __restrict__ xhigh,
               const float* __restrict__ Wl, const float* __restrict__ bl,
               const float* __restrict__ Wh, const float* __restrict__ bh,
               unsigned short* __restrict__ KThi, unsigned short* __restrict__ KTlo,
               unsigned short* __restrict__ QThi, unsigned short* __restrict__ QTlo,
               unsigned short* __restrict__ Vc, float* __restrict__ R32)
{
    const int id = blockIdx.x;
    const int b  = id & 7;        // XCD = linear_id % 8 -> one batch per XCD
    const int nb = id >> 3;       // 0..63
    const int t  = threadIdx.x;   // 0..63
    const int n  = nb * 64 + t;

    for (int pass = 0; pass < 2; ++pass) {
        const float* __restrict__ x    = pass ? xhigh : xlow;
        const float* __restrict__ W    = pass ? Wh : Wl;
        const float* __restrict__ bias = pass ? bh : bl;

        float xr[64];
#pragma unroll
        for (int i = 0; i < 64; ++i)
            xr[i] = x[((size_t)(b * 64 + i)) * NPOS + n];

        unsigned hpack[32], lpack[32];
#pragma unroll
        for (int o = 0; o < 64; ++o) {
            float acc = bias[o];
#pragma unroll
            for (int i = 0; i < 64; ++i)
                acc = fmaf(W[o * 64 + i], xr[i], acc);   // W reads are wave-uniform -> s_load

            unsigned short h  = bf_rne(acc);
            unsigned short lo = bf_rne(acc - bf_f(h));
            if (o & 1) { hpack[o >> 1] |= ((unsigned)h)  << 16; lpack[o >> 1] |= ((unsigned)lo) << 16; }
            else       { hpack[o >> 1]  = h;                    lpack[o >> 1]  = lo; }

            if (pass) {  // Bf extras: V (bf16) + residual (f32), channel-major, coalesced
                Vc [((size_t)(b * 64 + o)) * NPOS + n] = h;
                R32[((size_t)(b * 64 + o)) * NPOS + n] = acc;
            }
        }

        unsigned short* dh = pass ? QThi : KThi;
        unsigned short* dl = pass ? QTlo : KTlo;
        uint4* ph = (uint4*)(dh + ((size_t)(b * NPOS + n)) * 64);
        uint4* pl = (uint4*)(dl + ((size_t)(b * NPOS + n)) * 64);
#pragma unroll
        for (int q = 0; q < 8; ++q) {
            uint4 v; v.x = hpack[4*q]; v.y = hpack[4*q+1]; v.z = hpack[4*q+2]; v.w = hpack[4*q+3];
            ph[q] = v;
            uint4 u; u.x = lpack[4*q]; u.y = lpack[4*q+1]; u.z = lpack[4*q+2]; u.w = lpack[4*q+3];
            pl[q] = u;
        }
    }
}

// ---------------------------------------------------------------------------
// Kernel 2: fused flash attention + residual. Block = 256 threads (4 waves),
// 64 q-rows per block (16 per wave), KV tile = 64. mfma_f32_16x16x32_bf16.
// S tile per wave: M=16 (q rows) x N=64 (kv cols), compensated bf16 QK^T.
// C layout (verified, guide m89): col = lane&15, row = (lane>>4)*4 + reg.
// A/B frag: row/col = lane&15, k = (lane>>4)*8 + e (8 consecutive).
// ---------------------------------------------------------------------------
__global__ __launch_bounds__(256)
void attn_fused(const unsigned short* __restrict__ KThi, const unsigned short* __restrict__ KTlo,
                const unsigned short* __restrict__ QThi, const unsigned short* __restrict__ QTlo,
                const unsigned short* __restrict__ Vc, const float* __restrict__ R32,
                float* __restrict__ out)
{
    const int id   = blockIdx.x;
    const int b    = id & 7;       // one batch per XCD
    const int qb   = id >> 3;      // 0..63: q-tile index
    const int tid  = threadIdx.x;
    const int w    = tid >> 6;     // wave 0..3
    const int lane = tid & 63;
    const int l16  = lane & 15;
    const int g    = lane >> 4;    // 0..3

    __shared__ unsigned short Plds[4][16][72];  // per-wave P transpose staging (bf16)
    __shared__ float Olds[64][68];              // epilogue transpose

    const int qrow = qb * 64 + w * 16 + l16;

    // Q fragments (hoisted): rows qrow, k = kk*32 + g*8 .. +8
    bf16x8 qhi[2], qlo[2];
    {
        const unsigned short* qp = QThi + ((size_t)(b * NPOS + qrow)) * 64 + g * 8;
        const unsigned short* qq = QTlo + ((size_t)(b * NPOS + qrow)) * 64 + g * 8;
        qhi[0] = *(const bf16x8*)qp;        qhi[1] = *(const bf16x8*)(qp + 32);
        qlo[0] = *(const bf16x8*)qq;        qlo[1] = *(const bf16x8*)(qq + 32);
    }

    f32x4 accO[4];
#pragma unroll
    for (int df = 0; df < 4; ++df) accO[df] = (f32x4){0.f, 0.f, 0.f, 0.f};
    float m_r[4], l_r[4];
#pragma unroll
    for (int r = 0; r < 4; ++r) { m_r[r] = -1e30f; l_r[r] = 0.f; }

    for (int kt = 0; kt < 64; ++kt) {
        const int j0 = kt * 64;

        // ---- QK^T (compensated: qh*kh + ql*kh + qh*kl) ----
        f32x4 sA[4];
#pragma unroll
        for (int jf = 0; jf < 4; ++jf) sA[jf] = (f32x4){0.f, 0.f, 0.f, 0.f};
#pragma unroll
        for (int kk = 0; kk < 2; ++kk) {
#pragma unroll
            for (int jf = 0; jf < 4; ++jf) {
                const size_t roff = ((size_t)(b * NPOS + j0 + jf * 16 + l16)) * 64 + kk * 32 + g * 8;
                bf16x8 khi = *(const bf16x8*)(KThi + roff);
                bf16x8 klo = *(const bf16x8*)(KTlo + roff);
                sA[jf] = __builtin_amdgcn_mfma_f32_16x16x32_bf16(qhi[kk], khi, sA[jf], 0, 0, 0);
                sA[jf] = __builtin_amdgcn_mfma_f32_16x16x32_bf16(qlo[kk], khi, sA[jf], 0, 0, 0);
                sA[jf] = __builtin_amdgcn_mfma_f32_16x16x32_bf16(qhi[kk], klo, sA[jf], 0, 0, 0);
            }
        }

        // ---- online softmax: row i = g*4+r, cols spread over l16 x jf ----
        float pmax[4];
#pragma unroll
        for (int r = 0; r < 4; ++r)
            pmax[r] = fmaxf(fmaxf(sA[0][r], sA[1][r]), fmaxf(sA[2][r], sA[3][r]));
#pragma unroll
        for (int mask = 1; mask <= 8; mask <<= 1)
#pragma unroll
            for (int r = 0; r < 4; ++r)
                pmax[r] = fmaxf(pmax[r], __shfl_xor(pmax[r], mask, 64));

        float sc[4];
#pragma unroll
        for (int r = 0; r < 4; ++r) {
            float nm = fmaxf(m_r[r], pmax[r]);
            sc[r] = __expf(m_r[r] - nm);
            m_r[r] = nm;
        }

        float ps[4] = {0.f, 0.f, 0.f, 0.f};
        unsigned short pb[4][4];
#pragma unroll
        for (int jf = 0; jf < 4; ++jf)
#pragma unroll
            for (int r = 0; r < 4; ++r) {
                float p = __expf(sA[jf][r] - m_r[r]);
                ps[r] += p;
                pb[jf][r] = bf_rne(p);
            }
#pragma unroll
        for (int mask = 1; mask <= 8; mask <<= 1)
#pragma unroll
            for (int r = 0; r < 4; ++r)
                ps[r] += __shfl_xor(ps[r], mask, 64);
#pragma unroll
        for (int r = 0; r < 4; ++r) l_r[r] = l_r[r] * sc[r] + ps[r];
#pragma unroll
        for (int df = 0; df < 4; ++df)
#pragma unroll
            for (int r = 0; r < 4; ++r) accO[df][r] *= sc[r];

        // ---- transpose P via per-wave LDS (C layout -> A-frag layout) ----
#pragma unroll
        for (int jf = 0; jf < 4; ++jf)
#pragma unroll
            for (int r = 0; r < 4; ++r)
                Plds[w][g * 4 + r][jf * 16 + l16] = pb[jf][r];

        // ---- PV ----
#pragma unroll
        for (int kk = 0; kk < 2; ++kk) {
            bf16x8 pf = *(const bf16x8*)&Plds[w][l16][kk * 32 + g * 8];
#pragma unroll
            for (int df = 0; df < 4; ++df) {
                const unsigned short* vp =
                    Vc + ((size_t)(b * 64 + df * 16 + l16)) * NPOS + j0 + kk * 32 + g * 8;
                bf16x8 vf = *(const bf16x8*)vp;
                accO[df] = __builtin_amdgcn_mfma_f32_16x16x32_bf16(pf, vf, accO[df], 0, 0, 0);
            }
        }
    }

    // ---- epilogue: normalize, transpose via LDS, add residual, store ----
    float inv[4];
#pragma unroll
    for (int r = 0; r < 4; ++r) inv[r] = 1.0f / l_r[r];
#pragma unroll
    for (int df = 0; df < 4; ++df)
#pragma unroll
        for (int r = 0; r < 4; ++r)
            Olds[w * 16 + g * 4 + r][df * 16 + l16] = accO[df][r] * inv[r];
    __syncthreads();

    const int d   = tid >> 2;
    const int seg = tid & 3;
    const size_t obase = ((size_t)(b * 64 + d)) * NPOS + qb * 64 + seg * 16;
    const f32x4* rp = (const f32x4*)(R32 + obase);
    f32x4*       op = (f32x4*)(out + obase);
#pragma unroll
    for (int q = 0; q < 4; ++q) {
        f32x4 rv = rp[q];
        f32x4 v;
#pragma unroll
        for (int e = 0; e < 4; ++e)
            v[e] = Olds[seg * 16 + q * 4 + e][d] + rv[e];
        op[q] = v;
    }
}

// ---------------------------------------------------------------------------
extern "C" void kernel_launch(void* const* d_in, const int* in_sizes, int n_in,
                              void* d_out, int out_size, void* d_ws, size_t ws_size,
                              hipStream_t stream)
{
    const float* xlow  = (const float*)d_in[0];
    const float* xhigh = (const float*)d_in[1];
    const float* Wl    = (const float*)d_in[2];
    const float* bl    = (const float*)d_in[3];
    const float* Wh    = (const float*)d_in[4];
    const float* bh    = (const float*)d_in[5];

    char* ws = (char*)d_ws;
    unsigned short* KThi = (unsigned short*)(ws);
    unsigned short* KTlo = (unsigned short*)(ws + ( 4u << 20));
    unsigned short* QThi = (unsigned short*)(ws + ( 8u << 20));
    unsigned short* QTlo = (unsigned short*)(ws + (12u << 20));
    unsigned short* Vc   = (unsigned short*)(ws + (16u << 20));
    float*          R32  = (float*)         (ws + (20u << 20));   // 8 MB -> 28 MB total

    conv_prep<<<dim3(512), dim3(64), 0, stream>>>(
        xlow, xhigh, Wl, bl, Wh, bh, KThi, KTlo, QThi, QTlo, Vc, R32);
    attn_fused<<<dim3(512), dim3(256), 0, stream>>>(
        KThi, KTlo, QThi, QTlo, Vc, R32, (float*)d_out);
}

// Round 2
// 427.655 us; speedup vs baseline: 1.1898x; 1.1898x over previous
//
#include <hip/hip_runtime.h>
#include <hip/hip_bf16.h>
#include <stdint.h>

#define BATCH 8
#define NPOS 4096   // H*W = 64*64

typedef __attribute__((ext_vector_type(4))) float f32x4;
typedef __attribute__((ext_vector_type(8))) short bf16x8;

__device__ __forceinline__ unsigned short bf_rne(float f) {
    unsigned u = __float_as_uint(f);
    u += 0x7fffu + ((u >> 16) & 1u);
    return (unsigned short)(u >> 16);
}
__device__ __forceinline__ float bf_f(unsigned short s) {
    return __uint_as_float(((unsigned)s) << 16);
}

// ---------------------------------------------------------------------------
// Kernel 1: both 1x1 convs, parallelized over (batch, 64-pos block, pass,
// channel-quarter). Block = 64 threads; thread t owns position n, computes
// 16 output channels. W/bias reads are wave-uniform -> s_load.
// Writes:
//   KThi/KTlo [B][N][64] bf16 (A = low conv, transposed)   -> K operand
//   QThi/QTlo [B][N][64] bf16 (Bf = high conv, transposed) -> Q operand
//   Vc        [B][64][N] bf16 (Bf, channel-major)          -> V operand
//   R32       [B][64][N] f32  (Bf, channel-major)          -> residual
// ---------------------------------------------------------------------------
__global__ __launch_bounds__(64)
void conv_prep(const float* __restrict__ xlow, const float* __restrict__ xhigh,
               const float* __restrict__ Wl, const float* __restrict__ bl,
               const float* __restrict__ Wh, const float* __restrict__ bh,
               unsigned short* __restrict__ KThi, unsigned short* __restrict__ KTlo,
               unsigned short* __restrict__ QThi, unsigned short* __restrict__ QTlo,
               unsigned short* __restrict__ Vc, float* __restrict__ R32)
{
    const int id   = blockIdx.x;
    const int b    = id & 7;          // XCD = id % 8 -> one batch per XCD
    const int rest = id >> 3;
    const int nb   = rest & 63;       // 0..63 position block
    const int pass = (rest >> 6) & 1; // 0 = low (K), 1 = high (Q/V/R)
    const int oq   = rest >> 7;       // 0..3 channel quarter
    const int t    = threadIdx.x;
    const int n    = nb * 64 + t;
    const int o0   = oq * 16;

    const float* __restrict__ x    = pass ? xhigh : xlow;
    const float* __restrict__ W    = pass ? Wh : Wl;
    const float* __restrict__ bias = pass ? bh : bl;

    float xr[64];
#pragma unroll
    for (int i = 0; i < 64; ++i)
        xr[i] = x[((size_t)(b * 64 + i)) * NPOS + n];

    unsigned hpack[8], lpack[8];
#pragma unroll
    for (int oo = 0; oo < 16; ++oo) {
        const int o = o0 + oo;
        float acc = bias[o];
#pragma unroll
        for (int i = 0; i < 64; ++i)
            acc = fmaf(W[o * 64 + i], xr[i], acc);

        unsigned short h  = bf_rne(acc);
        unsigned short lo = bf_rne(acc - bf_f(h));
        if (oo & 1) { hpack[oo >> 1] |= ((unsigned)h)  << 16; lpack[oo >> 1] |= ((unsigned)lo) << 16; }
        else        { hpack[oo >> 1]  = h;                    lpack[oo >> 1]  = lo; }

        if (pass) {
            Vc [((size_t)(b * 64 + o)) * NPOS + n] = h;
            R32[((size_t)(b * 64 + o)) * NPOS + n] = acc;
        }
    }

    unsigned short* dh = pass ? QThi : KThi;
    unsigned short* dl = pass ? QTlo : KTlo;
    uint4* ph = (uint4*)(dh + ((size_t)(b * NPOS + n)) * 64 + o0);
    uint4* pl = (uint4*)(dl + ((size_t)(b * NPOS + n)) * 64 + o0);
#pragma unroll
    for (int q = 0; q < 2; ++q) {
        uint4 v; v.x = hpack[4*q]; v.y = hpack[4*q+1]; v.z = hpack[4*q+2]; v.w = hpack[4*q+3];
        ph[q] = v;
        uint4 u; u.x = lpack[4*q]; u.y = lpack[4*q+1]; u.z = lpack[4*q+2]; u.w = lpack[4*q+3];
        pl[q] = u;
    }
}

// ---------------------------------------------------------------------------
// Kernel 2: flash attention partials. Block = 256 threads (4 waves), 64 q-rows
// per block (16/wave), KV tile 64, nsplit blocks cover the 64 KV tiles.
// Writes unnormalized accO (transposed to [d][n]) + running m, l per row.
// mfma_f32_16x16x32_bf16; C layout: col=lane&15, row=(lane>>4)*4+reg.
// ---------------------------------------------------------------------------
__global__ __launch_bounds__(256)
void attn_fused(const unsigned short* __restrict__ KThi, const unsigned short* __restrict__ KTlo,
                const unsigned short* __restrict__ QThi, const unsigned short* __restrict__ QTlo,
                const unsigned short* __restrict__ Vc,
                float* __restrict__ Pacc, float* __restrict__ Mp, float* __restrict__ Lp,
                int nt)  // KV tiles per block
{
    const int id   = blockIdx.x;
    const int b    = id & 7;          // one batch per XCD
    const int rest = id >> 3;
    const int qb   = rest & 63;       // q-tile
    const int s    = rest >> 6;       // KV split index
    const int tid  = threadIdx.x;
    const int w    = tid >> 6;
    const int lane = tid & 63;
    const int l16  = lane & 15;
    const int g    = lane >> 4;

    // LDS union: Plds (in-loop) and Olds (epilogue) never live simultaneously
    __shared__ float OldsBuf[64][68];                       // 17408 B
    unsigned short (*Plds)[16][72] = (unsigned short (*)[16][72])OldsBuf;

    const int qrow = qb * 64 + w * 16 + l16;

    bf16x8 qhi[2], qlo[2];
    {
        const unsigned short* qp = QThi + ((size_t)(b * NPOS + qrow)) * 64 + g * 8;
        const unsigned short* qq = QTlo + ((size_t)(b * NPOS + qrow)) * 64 + g * 8;
        qhi[0] = *(const bf16x8*)qp;        qhi[1] = *(const bf16x8*)(qp + 32);
        qlo[0] = *(const bf16x8*)qq;        qlo[1] = *(const bf16x8*)(qq + 32);
    }

    f32x4 accO[4];
#pragma unroll
    for (int df = 0; df < 4; ++df) accO[df] = (f32x4){0.f, 0.f, 0.f, 0.f};
    float m_r[4], l_r[4];
#pragma unroll
    for (int r = 0; r < 4; ++r) { m_r[r] = -1e30f; l_r[r] = 0.f; }

    for (int kt = s * nt; kt < s * nt + nt; ++kt) {
        const int j0 = kt * 64;

        // ---- QK^T (compensated: qh*kh + ql*kh + qh*kl) ----
        f32x4 sA[4];
#pragma unroll
        for (int jf = 0; jf < 4; ++jf) sA[jf] = (f32x4){0.f, 0.f, 0.f, 0.f};
#pragma unroll
        for (int kk = 0; kk < 2; ++kk) {
#pragma unroll
            for (int jf = 0; jf < 4; ++jf) {
                const size_t roff = ((size_t)(b * NPOS + j0 + jf * 16 + l16)) * 64 + kk * 32 + g * 8;
                bf16x8 khi = *(const bf16x8*)(KThi + roff);
                bf16x8 klo = *(const bf16x8*)(KTlo + roff);
                sA[jf] = __builtin_amdgcn_mfma_f32_16x16x32_bf16(qhi[kk], khi, sA[jf], 0, 0, 0);
                sA[jf] = __builtin_amdgcn_mfma_f32_16x16x32_bf16(qlo[kk], khi, sA[jf], 0, 0, 0);
                sA[jf] = __builtin_amdgcn_mfma_f32_16x16x32_bf16(qhi[kk], klo, sA[jf], 0, 0, 0);
            }
        }

        // ---- online softmax ----
        float pmax[4];
#pragma unroll
        for (int r = 0; r < 4; ++r)
            pmax[r] = fmaxf(fmaxf(sA[0][r], sA[1][r]), fmaxf(sA[2][r], sA[3][r]));
#pragma unroll
        for (int mask = 1; mask <= 8; mask <<= 1)
#pragma unroll
            for (int r = 0; r < 4; ++r)
                pmax[r] = fmaxf(pmax[r], __shfl_xor(pmax[r], mask, 64));

        float sc[4];
#pragma unroll
        for (int r = 0; r < 4; ++r) {
            float nm = fmaxf(m_r[r], pmax[r]);
            sc[r] = __expf(m_r[r] - nm);
            m_r[r] = nm;
        }

        float ps[4] = {0.f, 0.f, 0.f, 0.f};
        unsigned short pb[4][4];
#pragma unroll
        for (int jf = 0; jf < 4; ++jf)
#pragma unroll
            for (int r = 0; r < 4; ++r) {
                float p = __expf(sA[jf][r] - m_r[r]);
                ps[r] += p;
                pb[jf][r] = bf_rne(p);
            }
#pragma unroll
        for (int mask = 1; mask <= 8; mask <<= 1)
#pragma unroll
            for (int r = 0; r < 4; ++r)
                ps[r] += __shfl_xor(ps[r], mask, 64);
#pragma unroll
        for (int r = 0; r < 4; ++r) l_r[r] = l_r[r] * sc[r] + ps[r];
#pragma unroll
        for (int df = 0; df < 4; ++df)
#pragma unroll
            for (int r = 0; r < 4; ++r) accO[df][r] *= sc[r];

        // ---- transpose P via per-wave LDS slice ----
#pragma unroll
        for (int jf = 0; jf < 4; ++jf)
#pragma unroll
            for (int r = 0; r < 4; ++r)
                Plds[w][g * 4 + r][jf * 16 + l16] = pb[jf][r];

        // ---- PV ----
#pragma unroll
        for (int kk = 0; kk < 2; ++kk) {
            bf16x8 pf = *(const bf16x8*)&Plds[w][l16][kk * 32 + g * 8];
#pragma unroll
            for (int df = 0; df < 4; ++df) {
                const unsigned short* vp =
                    Vc + ((size_t)(b * 64 + df * 16 + l16)) * NPOS + j0 + kk * 32 + g * 8;
                bf16x8 vf = *(const bf16x8*)vp;
                accO[df] = __builtin_amdgcn_mfma_f32_16x16x32_bf16(pf, vf, accO[df], 0, 0, 0);
            }
        }
    }

    // ---- epilogue: write m/l, transpose accO via LDS, store partial ----
    if (l16 == 0) {
#pragma unroll
        for (int r = 0; r < 4; ++r) {
            Mp[(size_t)id * 64 + w * 16 + g * 4 + r] = m_r[r];
            Lp[(size_t)id * 64 + w * 16 + g * 4 + r] = l_r[r];
        }
    }

    __syncthreads();   // Plds (union) last read above -> Olds writes below
#pragma unroll
    for (int df = 0; df < 4; ++df)
#pragma unroll
        for (int r = 0; r < 4; ++r)
            OldsBuf[w * 16 + g * 4 + r][df * 16 + l16] = accO[df][r];
    __syncthreads();

    const int d   = tid >> 2;
    const int seg = tid & 3;
    float* op = Pacc + (size_t)id * 4096 + d * 64 + seg * 16;
#pragma unroll
    for (int q = 0; q < 4; ++q) {
        f32x4 v;
#pragma unroll
        for (int e = 0; e < 4; ++e)
            v[e] = OldsBuf[seg * 16 + q * 4 + e][d];
        *(f32x4*)(op + q * 4) = v;
    }
}

// ---------------------------------------------------------------------------
// Kernel 3: combine partials across splits + residual add.
// Block = (b, qb): 64 rows x 64 channels. Partial block p(s) = ((s*64+qb)<<3)|b.
// ---------------------------------------------------------------------------
__global__ __launch_bounds__(256)
void attn_combine(const float* __restrict__ Pacc, const float* __restrict__ Mp,
                  const float* __restrict__ Lp, const float* __restrict__ R32,
                  float* __restrict__ out, int nsplit)
{
    const int cid = blockIdx.x;
    const int b   = cid & 7;
    const int qb  = cid >> 3;
    const int t   = threadIdx.x;

    __shared__ float wgt[4][64];
    __shared__ float invL[64];

    if (t < 64) {
        float m = -1e30f;
        for (int s = 0; s < nsplit; ++s)
            m = fmaxf(m, Mp[(size_t)(((s * 64 + qb) << 3) | b) * 64 + t]);
        float L = 0.f;
        for (int s = 0; s < nsplit; ++s) {
            size_t p = (size_t)(((s * 64 + qb) << 3) | b);
            float wv = __expf(Mp[p * 64 + t] - m);
            wgt[s][t] = wv;
            L += wv * Lp[p * 64 + t];
        }
        invL[t] = 1.0f / L;
    }
    __syncthreads();

    const int c   = t >> 2;
    const int seg = t & 3;
    const size_t obase = ((size_t)(b * 64 + c)) * NPOS + qb * 64 + seg * 16;
    const f32x4* rp = (const f32x4*)(R32 + obase);
    f32x4*       op = (f32x4*)(out + obase);
#pragma unroll
    for (int q = 0; q < 4; ++q) {
        const int n0 = seg * 16 + q * 4;
        f32x4 acc = (f32x4){0.f, 0.f, 0.f, 0.f};
        for (int s = 0; s < nsplit; ++s) {
            size_t p = (size_t)(((s * 64 + qb) << 3) | b);
            f32x4 pa = *(const f32x4*)(Pacc + p * 4096 + c * 64 + n0);
#pragma unroll
            for (int e = 0; e < 4; ++e)
                acc[e] += wgt[s][n0 + e] * pa[e];
        }
        f32x4 rv = rp[q];
        f32x4 v;
#pragma unroll
        for (int e = 0; e < 4; ++e)
            v[e] = acc[e] * invL[n0 + e] + rv[e];
        op[q] = v;
    }
}

// ---------------------------------------------------------------------------
extern "C" void kernel_launch(void* const* d_in, const int* in_sizes, int n_in,
                              void* d_out, int out_size, void* d_ws, size_t ws_size,
                              hipStream_t stream)
{
    const float* xlow  = (const float*)d_in[0];
    const float* xhigh = (const float*)d_in[1];
    const float* Wl    = (const float*)d_in[2];
    const float* bl    = (const float*)d_in[3];
    const float* Wh    = (const float*)d_in[4];
    const float* bh    = (const float*)d_in[5];

    char* ws = (char*)d_ws;
    unsigned short* KThi = (unsigned short*)(ws);
    unsigned short* KTlo = (unsigned short*)(ws + ( 4u << 20));
    unsigned short* QThi = (unsigned short*)(ws + ( 8u << 20));
    unsigned short* QTlo = (unsigned short*)(ws + (12u << 20));
    unsigned short* Vc   = (unsigned short*)(ws + (16u << 20));
    float*          R32  = (float*)         (ws + (20u << 20));   // 8 MB -> ends at 28 MB

    const size_t base = (size_t)28u << 20;
    // choose split by available workspace
    int nsplit = 4;
    {
        size_t gridA = (size_t)512 * 4;
        size_t need  = base + gridA * 4096 * 4 + 2 * gridA * 64 * 4;
        if (ws_size < need) nsplit = 1;
    }
    const size_t gridA = (size_t)512 * nsplit;
    float* Pacc = (float*)(ws + base);
    float* Mp   = (float*)(ws + base + gridA * 4096 * 4);
    float* Lp   = (float*)(ws + base + gridA * 4096 * 4 + gridA * 64 * 4);

    conv_prep<<<dim3(4096), dim3(64), 0, stream>>>(
        xlow, xhigh, Wl, bl, Wh, bh, KThi, KTlo, QThi, QTlo, Vc, R32);
    attn_fused<<<dim3((unsigned)gridA), dim3(256), 0, stream>>>(
        KThi, KTlo, QThi, QTlo, Vc, Pacc, Mp, Lp, 64 / nsplit);
    attn_combine<<<dim3(512), dim3(256), 0, stream>>>(
        Pacc, Mp, Lp, R32, (float*)d_out, nsplit);
}

// Round 3
// 161.248 us; speedup vs baseline: 3.1554x; 2.6522x over previous
//
#include <hip/hip_runtime.h>
#include <hip/hip_bf16.h>
#include <stdint.h>

#define BATCH 8
#define NPOS 4096   // H*W = 64*64
#define LOG2E 1.4426950408889634f

typedef __attribute__((ext_vector_type(4)))  float f32x4;
typedef __attribute__((ext_vector_type(16))) float f32x16;
typedef __attribute__((ext_vector_type(8)))  short bf16x8;

__device__ __forceinline__ unsigned short bf_rne(float f) {
    unsigned u = __float_as_uint(f);
    u += 0x7fffu + ((u >> 16) & 1u);
    return (unsigned short)(u >> 16);
}
__device__ __forceinline__ float bf_f(unsigned short s) {
    return __uint_as_float(((unsigned)s) << 16);
}

// ---------------------------------------------------------------------------
// Kernel 1: both 1x1 convs (unchanged from round 2 — fast enough).
//   KThi/KTlo [B][N][64] bf16, QThi/QTlo [B][N][64] bf16,
//   Vc [B][64][N] bf16, R32 [B][64][N] f32
// ---------------------------------------------------------------------------
__global__ __launch_bounds__(64)
void conv_prep(const float* __restrict__ xlow, const float* __restrict__ xhigh,
               const float* __restrict__ Wl, const float* __restrict__ bl,
               const float* __restrict__ Wh, const float* __restrict__ bh,
               unsigned short* __restrict__ KThi, unsigned short* __restrict__ KTlo,
               unsigned short* __restrict__ QThi, unsigned short* __restrict__ QTlo,
               unsigned short* __restrict__ Vc, float* __restrict__ R32)
{
    const int id   = blockIdx.x;
    const int b    = id & 7;
    const int rest = id >> 3;
    const int nb   = rest & 63;
    const int pass = (rest >> 6) & 1;
    const int oq   = rest >> 7;
    const int t    = threadIdx.x;
    const int n    = nb * 64 + t;
    const int o0   = oq * 16;

    const float* __restrict__ x    = pass ? xhigh : xlow;
    const float* __restrict__ W    = pass ? Wh : Wl;
    const float* __restrict__ bias = pass ? bh : bl;

    float xr[64];
#pragma unroll
    for (int i = 0; i < 64; ++i)
        xr[i] = x[((size_t)(b * 64 + i)) * NPOS + n];

    unsigned hpack[8], lpack[8];
#pragma unroll
    for (int oo = 0; oo < 16; ++oo) {
        const int o = o0 + oo;
        float acc = bias[o];
#pragma unroll
        for (int i = 0; i < 64; ++i)
            acc = fmaf(W[o * 64 + i], xr[i], acc);

        unsigned short h  = bf_rne(acc);
        unsigned short lo = bf_rne(acc - bf_f(h));
        if (oo & 1) { hpack[oo >> 1] |= ((unsigned)h)  << 16; lpack[oo >> 1] |= ((unsigned)lo) << 16; }
        else        { hpack[oo >> 1]  = h;                    lpack[oo >> 1]  = lo; }

        if (pass) {
            Vc [((size_t)(b * 64 + o)) * NPOS + n] = h;
            R32[((size_t)(b * 64 + o)) * NPOS + n] = acc;
        }
    }

    unsigned short* dh = pass ? QThi : KThi;
    unsigned short* dl = pass ? QTlo : KTlo;
    uint4* ph = (uint4*)(dh + ((size_t)(b * NPOS + n)) * 64 + o0);
    uint4* pl = (uint4*)(dl + ((size_t)(b * NPOS + n)) * 64 + o0);
#pragma unroll
    for (int q = 0; q < 2; ++q) {
        uint4 v; v.x = hpack[4*q]; v.y = hpack[4*q+1]; v.z = hpack[4*q+2]; v.w = hpack[4*q+3];
        ph[q] = v;
        uint4 u; u.x = lpack[4*q]; u.y = lpack[4*q+1]; u.z = lpack[4*q+2]; u.w = lpack[4*q+3];
        pl[q] = u;
    }
}

// ---------------------------------------------------------------------------
// LDS staging of one 64-key supertile (24 KB):
//   [0,4K) Khi(it=0) [4K,8K) Klo(0) [8K,12K) Khi(1) [12K,16K) Klo(1) [16K,24K) V
// K tiles: [32 keys][128B rows]; V: [64 ch][128B rows (64 keys)].
// XOR swizzle chunk^=(row&7) applied on the GLOBAL source (rule #21):
// LDS stays linear for global_load_lds; reads apply the same XOR.
// ---------------------------------------------------------------------------
__device__ __forceinline__ void stage_st(const unsigned short* __restrict__ KThi,
                                         const unsigned short* __restrict__ KTlo,
                                         const unsigned short* __restrict__ Vc,
                                         int b, int j0, char* dst, int w, int lane)
{
#pragma unroll
    for (int q = 0; q < 6; ++q) {
        const int S = w * 6 + q;               // 0..23, wave-uniform
        const unsigned short* src;
        if (S < 16) {
            const int it  = S >> 3;
            const int hl  = (S >> 2) & 1;
            const int E   = ((S & 3) << 6) | lane;
            const int row = E >> 3, c = E & 7;
            const unsigned short* base = hl ? KTlo : KThi;
            src = base + ((size_t)b * NPOS + j0 + it * 32 + row) * 64 + ((c ^ (row & 7)) << 3);
        } else {
            const int E   = ((S - 16) << 6) | lane;
            const int row = E >> 3, c = E & 7;
            src = Vc + ((size_t)(b * 64 + row)) * NPOS + j0 + ((c ^ (row & 7)) << 3);
        }
        __builtin_amdgcn_global_load_lds(
            (const __attribute__((address_space(1))) unsigned int*)(const void*)src,
            (__attribute__((address_space(3))) unsigned int*)(void*)(dst + S * 1024),
            16, 0, 0);
    }
}

// ---------------------------------------------------------------------------
// Kernel 2: flash attention partials. 4 waves x 32 q-rows = 128 q/block.
// mfma_f32_32x32x16_bf16, swapped operands:
//   S = K·Q  -> C[key][q]: col=lane&31=q (lane owns ONE q-row)
//   O^T = V^T·P -> C[d][q]: col=lane&31=q (rescale is per-lane)
// A/B frag: row/col=lane&31, k=(lane>>5)*8+e.
// C row = (reg&3)+8*(reg>>2)+4*(lane>>5)  [m74/m101 verified]
// ---------------------------------------------------------------------------
__global__ __launch_bounds__(256, 3)
void attn_fused(const unsigned short* __restrict__ KThi, const unsigned short* __restrict__ KTlo,
                const unsigned short* __restrict__ QThi, const unsigned short* __restrict__ QTlo,
                const unsigned short* __restrict__ Vc,
                float* __restrict__ Pacc, float* __restrict__ Mp, float* __restrict__ Lp,
                int nst)   // 64-key supertiles per block
{
    const int id   = blockIdx.x;
    const int b    = id & 7;            // one batch per XCD
    const int qb   = (id >> 3) & 31;    // q-tile (128 rows)
    const int s    = id >> 8;           // KV split index
    const int tid  = threadIdx.x;
    const int w    = tid >> 6;
    const int lane = tid & 63;
    const int r31  = lane & 31;
    const int g2   = lane >> 5;

    __shared__ __align__(1024) char smem[49152];   // 2 x 24KB supertile buffers

    // Q fragments hoisted (B-operand: col=lane&31=q, k=(lane>>5)*8+e)
    const int qrow = qb * 128 + w * 32 + r31;
    bf16x8 qhi[4], qlo[4];
#pragma unroll
    for (int kk = 0; kk < 4; ++kk) {
        const size_t qoff = ((size_t)b * NPOS + qrow) * 64 + kk * 16 + g2 * 8;
        qhi[kk] = *(const bf16x8*)(QThi + qoff);
        qlo[kk] = *(const bf16x8*)(QTlo + qoff);
    }

    f32x16 accO0, accO1;
#pragma unroll
    for (int r = 0; r < 16; ++r) { accO0[r] = 0.f; accO1[r] = 0.f; }
    float m_run = -1e30f, l_run = 0.f;

    const int st0 = s * nst;
    stage_st(KThi, KTlo, Vc, b, st0 * 64, smem, w, lane);
    __syncthreads();

    for (int st = 0; st < nst; ++st) {
        char* buf = smem + (st & 1) * 24576;
        if (st + 1 < nst)
            stage_st(KThi, KTlo, Vc, b, (st0 + st + 1) * 64, smem + ((st + 1) & 1) * 24576, w, lane);

#pragma unroll
        for (int it = 0; it < 2; ++it) {
            // ---- QK^T (compensated: kh*qh + kl*qh + kh*ql) ----
            f32x16 sA;
#pragma unroll
            for (int r = 0; r < 16; ++r) sA[r] = 0.f;
            const char* Kb = buf + it * 8192;
#pragma unroll
            for (int kk = 0; kk < 4; ++kk) {
                const int cb  = (kk << 1) | g2;
                const int off = r31 * 128 + ((cb ^ (r31 & 7)) << 4);
                bf16x8 kh = *(const bf16x8*)(Kb + off);
                bf16x8 kl = *(const bf16x8*)(Kb + 4096 + off);
                sA = __builtin_amdgcn_mfma_f32_32x32x16_bf16(kh, qhi[kk], sA, 0, 0, 0);
                sA = __builtin_amdgcn_mfma_f32_32x32x16_bf16(kl, qhi[kk], sA, 0, 0, 0);
                sA = __builtin_amdgcn_mfma_f32_32x32x16_bf16(kh, qlo[kk], sA, 0, 0, 0);
            }

            // ---- online softmax: lane owns q-row r31; 16 keys here, 16 in lane^32 ----
            float tmax = sA[0];
#pragma unroll
            for (int r = 1; r < 16; ++r) tmax = fmaxf(tmax, sA[r]);
            tmax = fmaxf(tmax, __shfl_xor(tmax, 32, 64));
            const float nm = fmaxf(m_run, tmax);
            const float sc = exp2f((m_run - nm) * LOG2E);
            m_run = nm;

            float p[16];
            float ps = 0.f;
#pragma unroll
            for (int r = 0; r < 16; ++r) {
                p[r] = exp2f((sA[r] - nm) * LOG2E);
                ps += p[r];
            }
            ps += __shfl_xor(ps, 32, 64);
            l_run = l_run * sc + ps;
#pragma unroll
            for (int r = 0; r < 16; ++r) { accO0[r] *= sc; accO1[r] *= sc; }

            // ---- P -> bf16 B-frags, in-register (pack + lane^32 exchange) ----
            unsigned wpk[8], y[8];
#pragma unroll
            for (int h = 0; h < 8; ++h)
                wpk[h] = (unsigned)bf_rne(p[2*h]) | ((unsigned)bf_rne(p[2*h+1]) << 16);
#pragma unroll
            for (int h = 0; h < 8; ++h)
                y[h] = __shfl_xor(wpk[h], 32, 64);

            union { unsigned u[4]; bf16x8 v; } fa0, fa1;
            fa0.u[0] = g2 ? y[2]   : wpk[0];
            fa0.u[1] = g2 ? y[3]   : wpk[1];
            fa0.u[2] = g2 ? wpk[2] : y[0];
            fa0.u[3] = g2 ? wpk[3] : y[1];
            fa1.u[0] = g2 ? y[6]   : wpk[4];
            fa1.u[1] = g2 ? y[7]   : wpk[5];
            fa1.u[2] = g2 ? wpk[6] : y[4];
            fa1.u[3] = g2 ? wpk[7] : y[5];

            // ---- PV: O^T += V^T · P ----
            {   // df = 0 (channels 0..31)
                const int ch = r31;
                const int c0 = (((it * 2 + 0) << 1) | g2) ^ (ch & 7);
                const int c1 = (((it * 2 + 1) << 1) | g2) ^ (ch & 7);
                bf16x8 vf0 = *(const bf16x8*)(buf + 16384 + ch * 128 + (c0 << 4));
                bf16x8 vf1 = *(const bf16x8*)(buf + 16384 + ch * 128 + (c1 << 4));
                accO0 = __builtin_amdgcn_mfma_f32_32x32x16_bf16(vf0, fa0.v, accO0, 0, 0, 0);
                accO0 = __builtin_amdgcn_mfma_f32_32x32x16_bf16(vf1, fa1.v, accO0, 0, 0, 0);
            }
            {   // df = 1 (channels 32..63)
                const int ch = 32 + r31;
                const int c0 = (((it * 2 + 0) << 1) | g2) ^ (ch & 7);
                const int c1 = (((it * 2 + 1) << 1) | g2) ^ (ch & 7);
                bf16x8 vf0 = *(const bf16x8*)(buf + 16384 + ch * 128 + (c0 << 4));
                bf16x8 vf1 = *(const bf16x8*)(buf + 16384 + ch * 128 + (c1 << 4));
                accO1 = __builtin_amdgcn_mfma_f32_32x32x16_bf16(vf0, fa0.v, accO1, 0, 0, 0);
                accO1 = __builtin_amdgcn_mfma_f32_32x32x16_bf16(vf1, fa1.v, accO1, 0, 0, 0);
            }
        }
        __syncthreads();   // drains vmcnt (stage st+1 done) + all LDS reads of buf
    }

    // ---- epilogue: unnormalized partials, O^T layout [64 d][128 q] ----
#pragma unroll
    for (int r = 0; r < 16; ++r) {
        const int d0 = (r & 3) + 8 * (r >> 2) + 4 * g2;
        Pacc[(size_t)id * 8192 + (size_t)d0 * 128 + w * 32 + r31]        = accO0[r];
        Pacc[(size_t)id * 8192 + (size_t)(d0 + 32) * 128 + w * 32 + r31] = accO1[r];
    }
    if (g2 == 0) {
        Mp[(size_t)id * 128 + w * 32 + r31] = m_run;
        Lp[(size_t)id * 128 + w * 32 + r31] = l_run;
    }
}

// ---------------------------------------------------------------------------
// Kernel 3: combine partials across splits + residual add.
// Block = (b, qb, channel-quarter). Partial block p(s) = (s<<8)|(qb<<3)|b.
// ---------------------------------------------------------------------------
__global__ __launch_bounds__(256)
void attn_combine(const float* __restrict__ Pacc, const float* __restrict__ Mp,
                  const float* __restrict__ Lp, const float* __restrict__ R32,
                  float* __restrict__ out, int nsplit)
{
    const int cid     = blockIdx.x;
    const int quarter = cid & 3;
    const int b       = (cid >> 2) & 7;
    const int qb      = cid >> 5;        // 0..31
    const int t       = threadIdx.x;

    __shared__ float wgt[4][128];
    __shared__ float invL[128];

    if (t < 128) {
        float m = -1e30f;
        for (int s = 0; s < nsplit; ++s)
            m = fmaxf(m, Mp[(size_t)((s << 8) | (qb << 3) | b) * 128 + t]);
        float L = 0.f;
        for (int s = 0; s < nsplit; ++s) {
            const size_t p = (size_t)((s << 8) | (qb << 3) | b);
            float wv = exp2f((Mp[p * 128 + t] - m) * LOG2E);
            wgt[s][t] = wv;
            L += wv * Lp[p * 128 + t];
        }
        invL[t] = 1.0f / L;
    }
    __syncthreads();

    const int c_loc = t >> 4;                // 0..15
    const int c     = quarter * 16 + c_loc;  // 0..63
    const int q0    = (t & 15) * 8;          // 0..120
    const size_t obase = ((size_t)(b * 64 + c)) * NPOS + qb * 128 + q0;

#pragma unroll
    for (int hv = 0; hv < 2; ++hv) {
        const int q = q0 + hv * 4;
        f32x4 acc = (f32x4){0.f, 0.f, 0.f, 0.f};
        for (int s = 0; s < nsplit; ++s) {
            const size_t p = (size_t)((s << 8) | (qb << 3) | b);
            f32x4 pa = *(const f32x4*)(Pacc + p * 8192 + (size_t)c * 128 + q);
#pragma unroll
            for (int e = 0; e < 4; ++e)
                acc[e] += wgt[s][q + e] * pa[e];
        }
        f32x4 rv = *(const f32x4*)(R32 + obase + hv * 4);
        f32x4 v;
#pragma unroll
        for (int e = 0; e < 4; ++e)
            v[e] = acc[e] * invL[q + e] + rv[e];
        *(f32x4*)(out + obase + hv * 4) = v;
    }
}

// ---------------------------------------------------------------------------
extern "C" void kernel_launch(void* const* d_in, const int* in_sizes, int n_in,
                              void* d_out, int out_size, void* d_ws, size_t ws_size,
                              hipStream_t stream)
{
    const float* xlow  = (const float*)d_in[0];
    const float* xhigh = (const float*)d_in[1];
    const float* Wl    = (const float*)d_in[2];
    const float* bl    = (const float*)d_in[3];
    const float* Wh    = (const float*)d_in[4];
    const float* bh    = (const float*)d_in[5];

    char* ws = (char*)d_ws;
    unsigned short* KThi = (unsigned short*)(ws);
    unsigned short* KTlo = (unsigned short*)(ws + ( 4u << 20));
    unsigned short* QThi = (unsigned short*)(ws + ( 8u << 20));
    unsigned short* QTlo = (unsigned short*)(ws + (12u << 20));
    unsigned short* Vc   = (unsigned short*)(ws + (16u << 20));
    float*          R32  = (float*)         (ws + (20u << 20));   // 8 MB -> ends at 28 MB

    const size_t base = (size_t)28u << 20;
    int nsplit = 4;
    {
        size_t nblk = (size_t)256 * 4;
        size_t need = base + nblk * 8192 * 4 + 2 * nblk * 128 * 4;
        if (ws_size < need) nsplit = 1;
    }
    const size_t nblk = (size_t)256 * nsplit;
    float* Pacc = (float*)(ws + base);
    float* Mp   = (float*)(ws + base + nblk * 8192 * 4);
    float* Lp   = (float*)(ws + base + nblk * 8192 * 4 + nblk * 128 * 4);

    conv_prep<<<dim3(4096), dim3(64), 0, stream>>>(
        xlow, xhigh, Wl, bl, Wh, bh, KThi, KTlo, QThi, QTlo, Vc, R32);
    attn_fused<<<dim3((unsigned)nblk), dim3(256), 0, stream>>>(
        KThi, KTlo, QThi, QTlo, Vc, Pacc, Mp, Lp, 64 / nsplit);
    attn_combine<<<dim3(1024), dim3(256), 0, stream>>>(
        Pacc, Mp, Lp, R32, (float*)d_out, nsplit);
}

// Round 4
// 159.604 us; speedup vs baseline: 3.1879x; 1.0103x over previous
//
#include <hip/hip_runtime.h>
#include <hip/hip_bf16.h>
#include <stdint.h>

#define BATCH 8
#define NPOS 4096   // H*W = 64*64
#define LOG2E 1.4426950408889634f

typedef __attribute__((ext_vector_type(4)))  float f32x4;
typedef __attribute__((ext_vector_type(16))) float f32x16;
typedef __attribute__((ext_vector_type(8)))  short bf16x8;

__device__ __forceinline__ unsigned short bf_rne(float f) {
    unsigned u = __float_as_uint(f);
    u += 0x7fffu + ((u >> 16) & 1u);
    return (unsigned short)(u >> 16);
}
__device__ __forceinline__ float bf_f(unsigned short s) {
    return __uint_as_float(((unsigned)s) << 16);
}
__device__ __forceinline__ unsigned cvt_pk_bf16(float lo, float hi) {
    unsigned r;
    asm("v_cvt_pk_bf16_f32 %0, %1, %2" : "=v"(r) : "v"(lo), "v"(hi));
    return r;
}

// ---------------------------------------------------------------------------
// Kernel 1: both 1x1 convs. Block = (b, nb, pass), 256 threads = 4 waves.
// Wave w computes channel-quarter w (W reads stay wave-uniform -> s_load).
// x panel (64ch x 64pos, 16KB) staged once in LDS, shared by all 4 waves.
//   KThi/KTlo [B][N][64] bf16, QThi/QTlo [B][N][64] bf16,
//   Vc [B][64][N] bf16, R32 [B][64][N] f32
// ---------------------------------------------------------------------------
__global__ __launch_bounds__(256)
void conv_prep(const float* __restrict__ xlow, const float* __restrict__ xhigh,
               const float* __restrict__ Wl, const float* __restrict__ bl,
               const float* __restrict__ Wh, const float* __restrict__ bh,
               unsigned short* __restrict__ KThi, unsigned short* __restrict__ KTlo,
               unsigned short* __restrict__ QThi, unsigned short* __restrict__ QTlo,
               unsigned short* __restrict__ Vc, float* __restrict__ R32)
{
    const int id   = blockIdx.x;
    const int b    = id & 7;
    const int rest = id >> 3;
    const int nb   = rest & 63;
    const int pass = rest >> 6;       // 0 = low (K), 1 = high (Q/V/R)
    const int t    = threadIdx.x;
    const int pos  = t & 63;
    const int oq   = t >> 6;          // wave index == channel quarter
    const int n    = nb * 64 + pos;
    const int o0   = oq * 16;

    const float* __restrict__ x    = pass ? xhigh : xlow;
    const float* __restrict__ W    = pass ? Wh : Wl;
    const float* __restrict__ bias = pass ? bh : bl;

    __shared__ float xs[64][65];      // [pos][ch], +1 pad

    {   // stage: thread t loads ch = t>>2, 16 consecutive floats (coalesced 256B/4thr)
        const int ch = t >> 2, seg = t & 3;
        const float* sp = x + ((size_t)(b * 64 + ch)) * NPOS + nb * 64 + seg * 16;
#pragma unroll
        for (int q = 0; q < 4; ++q) {
            f32x4 v = *(const f32x4*)(sp + q * 4);
#pragma unroll
            for (int e = 0; e < 4; ++e)
                xs[seg * 16 + q * 4 + e][ch] = v[e];
        }
    }
    __syncthreads();

    float xr[64];
#pragma unroll
    for (int i = 0; i < 16; ++i) {
        f32x4 v = *(const f32x4*)&xs[pos][i * 4];
#pragma unroll
        for (int e = 0; e < 4; ++e) xr[i * 4 + e] = v[e];
    }

    unsigned hpack[8], lpack[8];
#pragma unroll
    for (int oo = 0; oo < 16; ++oo) {
        const int o = o0 + oo;
        float acc = bias[o];
#pragma unroll
        for (int i = 0; i < 64; ++i)
            acc = fmaf(W[o * 64 + i], xr[i], acc);

        unsigned short h  = bf_rne(acc);
        unsigned short lo = bf_rne(acc - bf_f(h));
        if (oo & 1) { hpack[oo >> 1] |= ((unsigned)h)  << 16; lpack[oo >> 1] |= ((unsigned)lo) << 16; }
        else        { hpack[oo >> 1]  = h;                    lpack[oo >> 1]  = lo; }

        if (pass) {
            Vc [((size_t)(b * 64 + o)) * NPOS + n] = h;
            R32[((size_t)(b * 64 + o)) * NPOS + n] = acc;
        }
    }

    unsigned short* dh = pass ? QThi : KThi;
    unsigned short* dl = pass ? QTlo : KTlo;
    uint4* ph = (uint4*)(dh + ((size_t)(b * NPOS + n)) * 64 + o0);
    uint4* pl = (uint4*)(dl + ((size_t)(b * NPOS + n)) * 64 + o0);
#pragma unroll
    for (int q = 0; q < 2; ++q) {
        uint4 v; v.x = hpack[4*q]; v.y = hpack[4*q+1]; v.z = hpack[4*q+2]; v.w = hpack[4*q+3];
        ph[q] = v;
        uint4 u; u.x = lpack[4*q]; u.y = lpack[4*q+1]; u.z = lpack[4*q+2]; u.w = lpack[4*q+3];
        pl[q] = u;
    }
}

// ---------------------------------------------------------------------------
// LDS staging of one 64-key supertile (24 KB):
//   [0,4K) Khi(it=0) [4K,8K) Klo(0) [8K,12K) Khi(1) [12K,16K) Klo(1) [16K,24K) V
// K tiles: [32 keys][128B rows]; V: [64 ch][128B rows (64 keys)].
// XOR swizzle chunk^=(row&7) applied on the GLOBAL source (rule #21).
// ---------------------------------------------------------------------------
__device__ __forceinline__ void stage_st(const unsigned short* __restrict__ KThi,
                                         const unsigned short* __restrict__ KTlo,
                                         const unsigned short* __restrict__ Vc,
                                         int b, int j0, char* dst, int w, int lane)
{
#pragma unroll
    for (int q = 0; q < 6; ++q) {
        const int S = w * 6 + q;               // 0..23, wave-uniform
        const unsigned short* src;
        if (S < 16) {
            const int it  = S >> 3;
            const int hl  = (S >> 2) & 1;
            const int E   = ((S & 3) << 6) | lane;
            const int row = E >> 3, c = E & 7;
            const unsigned short* base = hl ? KTlo : KThi;
            src = base + ((size_t)b * NPOS + j0 + it * 32 + row) * 64 + ((c ^ (row & 7)) << 3);
        } else {
            const int E   = ((S - 16) << 6) | lane;
            const int row = E >> 3, c = E & 7;
            src = Vc + ((size_t)(b * 64 + row)) * NPOS + j0 + ((c ^ (row & 7)) << 3);
        }
        __builtin_amdgcn_global_load_lds(
            (const __attribute__((address_space(1))) unsigned int*)(const void*)src,
            (__attribute__((address_space(3))) unsigned int*)(void*)(dst + S * 1024),
            16, 0, 0);
    }
}

// ---------------------------------------------------------------------------
// Kernel 2: flash attention partials. 4 waves x 32 q-rows = 128 q/block.
// mfma_f32_32x32x16_bf16, swapped operands (lane owns ONE q-row in S and O^T).
// KV split 22/21/21 supertiles -> grid 768 = exactly 3 blocks/CU (no tail).
// ---------------------------------------------------------------------------
__global__ __launch_bounds__(256, 3)
void attn_fused(const unsigned short* __restrict__ KThi, const unsigned short* __restrict__ KTlo,
                const unsigned short* __restrict__ QThi, const unsigned short* __restrict__ QTlo,
                const unsigned short* __restrict__ Vc,
                float* __restrict__ Pacc, float* __restrict__ Mp, float* __restrict__ Lp,
                int nsplit)
{
    const int id   = blockIdx.x;
    const int b    = id & 7;            // one batch per XCD
    const int qb   = (id >> 3) & 31;    // q-tile (128 rows)
    const int s    = id >> 8;           // KV split index
    const int tid  = threadIdx.x;
    const int w    = tid >> 6;
    const int lane = tid & 63;
    const int r31  = lane & 31;
    const int g2   = lane >> 5;

    int st0, nst;
    if (nsplit == 1) { st0 = 0; nst = 64; }
    else             { st0 = s * 21 + (s > 0 ? 1 : 0); nst = (s == 0) ? 22 : 21; }

    __shared__ __align__(1024) char smem[49152];   // 2 x 24KB supertile buffers

    // Q fragments hoisted (B-operand: col=lane&31=q, k=(lane>>5)*8+e)
    const int qrow = qb * 128 + w * 32 + r31;
    bf16x8 qhi[4], qlo[4];
#pragma unroll
    for (int kk = 0; kk < 4; ++kk) {
        const size_t qoff = ((size_t)b * NPOS + qrow) * 64 + kk * 16 + g2 * 8;
        qhi[kk] = *(const bf16x8*)(QThi + qoff);
        qlo[kk] = *(const bf16x8*)(QTlo + qoff);
    }

    f32x16 accO0, accO1;
#pragma unroll
    for (int r = 0; r < 16; ++r) { accO0[r] = 0.f; accO1[r] = 0.f; }
    float m_run = -1e30f, l_run = 0.f;

    stage_st(KThi, KTlo, Vc, b, st0 * 64, smem, w, lane);
    __syncthreads();

    for (int st = 0; st < nst; ++st) {
        char* buf = smem + (st & 1) * 24576;
        if (st + 1 < nst)
            stage_st(KThi, KTlo, Vc, b, (st0 + st + 1) * 64, smem + ((st + 1) & 1) * 24576, w, lane);

#pragma unroll
        for (int it = 0; it < 2; ++it) {
            // ---- QK^T (compensated: kh*qh + kl*qh + kh*ql) ----
            f32x16 sA;
#pragma unroll
            for (int r = 0; r < 16; ++r) sA[r] = 0.f;
            const char* Kb = buf + it * 8192;
            __builtin_amdgcn_s_setprio(1);
#pragma unroll
            for (int kk = 0; kk < 4; ++kk) {
                const int cb  = (kk << 1) | g2;
                const int off = r31 * 128 + ((cb ^ (r31 & 7)) << 4);
                bf16x8 kh = *(const bf16x8*)(Kb + off);
                bf16x8 kl = *(const bf16x8*)(Kb + 4096 + off);
                sA = __builtin_amdgcn_mfma_f32_32x32x16_bf16(kh, qhi[kk], sA, 0, 0, 0);
                sA = __builtin_amdgcn_mfma_f32_32x32x16_bf16(kl, qhi[kk], sA, 0, 0, 0);
                sA = __builtin_amdgcn_mfma_f32_32x32x16_bf16(kh, qlo[kk], sA, 0, 0, 0);
            }
            __builtin_amdgcn_s_setprio(0);

            // ---- online softmax (lane owns q-row r31; 16 keys here, 16 in lane^32) ----
            float tmax = sA[0];
#pragma unroll
            for (int r = 1; r < 16; ++r) tmax = fmaxf(tmax, sA[r]);
            tmax = fmaxf(tmax, __shfl_xor(tmax, 32, 64));

            // defer-max (T13, THR=8): rescale only when the running max really grows
            if (!__all(tmax <= m_run + 8.0f)) {
                const float nm = fmaxf(m_run, tmax);
                const float sc = exp2f((m_run - nm) * LOG2E);
                m_run = nm;
                l_run *= sc;
#pragma unroll
                for (int r = 0; r < 16; ++r) { accO0[r] *= sc; accO1[r] *= sc; }
            }

            float p[16];
            float ps = 0.f;
#pragma unroll
            for (int r = 0; r < 16; ++r) {
                p[r] = exp2f((sA[r] - m_run) * LOG2E);
                ps += p[r];
            }
            ps += __shfl_xor(ps, 32, 64);
            l_run += ps;

            // ---- P -> bf16 B-frags in-register (cvt_pk + lane^32 exchange) ----
            unsigned wpk[8], y[8];
#pragma unroll
            for (int h = 0; h < 8; ++h)
                wpk[h] = cvt_pk_bf16(p[2*h], p[2*h+1]);
#pragma unroll
            for (int h = 0; h < 8; ++h)
                y[h] = __shfl_xor(wpk[h], 32, 64);

            union { unsigned u[4]; bf16x8 v; } fa0, fa1;
            fa0.u[0] = g2 ? y[2]   : wpk[0];
            fa0.u[1] = g2 ? y[3]   : wpk[1];
            fa0.u[2] = g2 ? wpk[2] : y[0];
            fa0.u[3] = g2 ? wpk[3] : y[1];
            fa1.u[0] = g2 ? y[6]   : wpk[4];
            fa1.u[1] = g2 ? y[7]   : wpk[5];
            fa1.u[2] = g2 ? wpk[6] : y[4];
            fa1.u[3] = g2 ? wpk[7] : y[5];

            // ---- PV: O^T += V^T · P ----
            __builtin_amdgcn_s_setprio(1);
            {   // channels 0..31
                const int ch = r31;
                const int c0 = (((it * 2 + 0) << 1) | g2) ^ (ch & 7);
                const int c1 = (((it * 2 + 1) << 1) | g2) ^ (ch & 7);
                bf16x8 vf0 = *(const bf16x8*)(buf + 16384 + ch * 128 + (c0 << 4));
                bf16x8 vf1 = *(const bf16x8*)(buf + 16384 + ch * 128 + (c1 << 4));
                accO0 = __builtin_amdgcn_mfma_f32_32x32x16_bf16(vf0, fa0.v, accO0, 0, 0, 0);
                accO0 = __builtin_amdgcn_mfma_f32_32x32x16_bf16(vf1, fa1.v, accO0, 0, 0, 0);
            }
            {   // channels 32..63
                const int ch = 32 + r31;
                const int c0 = (((it * 2 + 0) << 1) | g2) ^ (ch & 7);
                const int c1 = (((it * 2 + 1) << 1) | g2) ^ (ch & 7);
                bf16x8 vf0 = *(const bf16x8*)(buf + 16384 + ch * 128 + (c0 << 4));
                bf16x8 vf1 = *(const bf16x8*)(buf + 16384 + ch * 128 + (c1 << 4));
                accO1 = __builtin_amdgcn_mfma_f32_32x32x16_bf16(vf0, fa0.v, accO1, 0, 0, 0);
                accO1 = __builtin_amdgcn_mfma_f32_32x32x16_bf16(vf1, fa1.v, accO1, 0, 0, 0);
            }
            __builtin_amdgcn_s_setprio(0);
        }
        __syncthreads();   // drains vmcnt (stage st+1 done) + all LDS reads of buf
    }

    // ---- epilogue: unnormalized partials, O^T layout [64 d][128 q] ----
#pragma unroll
    for (int r = 0; r < 16; ++r) {
        const int d0 = (r & 3) + 8 * (r >> 2) + 4 * g2;
        Pacc[(size_t)id * 8192 + (size_t)d0 * 128 + w * 32 + r31]        = accO0[r];
        Pacc[(size_t)id * 8192 + (size_t)(d0 + 32) * 128 + w * 32 + r31] = accO1[r];
    }
    if (g2 == 0) {
        Mp[(size_t)id * 128 + w * 32 + r31] = m_run;
        Lp[(size_t)id * 128 + w * 32 + r31] = l_run;
    }
}

// ---------------------------------------------------------------------------
// Kernel 3: combine partials across splits + residual add.
// Block = (b, qb, channel-quarter). Partial block p(s) = (s<<8)|(qb<<3)|b.
// ---------------------------------------------------------------------------
__global__ __launch_bounds__(256)
void attn_combine(const float* __restrict__ Pacc, const float* __restrict__ Mp,
                  const float* __restrict__ Lp, const float* __restrict__ R32,
                  float* __restrict__ out, int nsplit)
{
    const int cid     = blockIdx.x;
    const int quarter = cid & 3;
    const int b       = (cid >> 2) & 7;
    const int qb      = cid >> 5;        // 0..31
    const int t       = threadIdx.x;

    __shared__ float wgt[4][128];
    __shared__ float invL[128];

    if (t < 128) {
        float m = -1e30f;
        for (int s = 0; s < nsplit; ++s)
            m = fmaxf(m, Mp[(size_t)((s << 8) | (qb << 3) | b) * 128 + t]);
        float L = 0.f;
        for (int s = 0; s < nsplit; ++s) {
            const size_t p = (size_t)((s << 8) | (qb << 3) | b);
            float wv = exp2f((Mp[p * 128 + t] - m) * LOG2E);
            wgt[s][t] = wv;
            L += wv * Lp[p * 128 + t];
        }
        invL[t] = 1.0f / L;
    }
    __syncthreads();

    const int c_loc = t >> 4;                // 0..15
    const int c     = quarter * 16 + c_loc;  // 0..63
    const int q0    = (t & 15) * 8;          // 0..120
    const size_t obase = ((size_t)(b * 64 + c)) * NPOS + qb * 128 + q0;

#pragma unroll
    for (int hv = 0; hv < 2; ++hv) {
        const int q = q0 + hv * 4;
        f32x4 acc = (f32x4){0.f, 0.f, 0.f, 0.f};
        for (int s = 0; s < nsplit; ++s) {
            const size_t p = (size_t)((s << 8) | (qb << 3) | b);
            f32x4 pa = *(const f32x4*)(Pacc + p * 8192 + (size_t)c * 128 + q);
#pragma unroll
            for (int e = 0; e < 4; ++e)
                acc[e] += wgt[s][q + e] * pa[e];
        }
        f32x4 rv = *(const f32x4*)(R32 + obase + hv * 4);
        f32x4 v;
#pragma unroll
        for (int e = 0; e < 4; ++e)
            v[e] = acc[e] * invL[q + e] + rv[e];
        *(f32x4*)(out + obase + hv * 4) = v;
    }
}

// ---------------------------------------------------------------------------
extern "C" void kernel_launch(void* const* d_in, const int* in_sizes, int n_in,
                              void* d_out, int out_size, void* d_ws, size_t ws_size,
                              hipStream_t stream)
{
    const float* xlow  = (const float*)d_in[0];
    const float* xhigh = (const float*)d_in[1];
    const float* Wl    = (const float*)d_in[2];
    const float* bl    = (const float*)d_in[3];
    const float* Wh    = (const float*)d_in[4];
    const float* bh    = (const float*)d_in[5];

    char* ws = (char*)d_ws;
    unsigned short* KThi = (unsigned short*)(ws);
    unsigned short* KTlo = (unsigned short*)(ws + ( 4u << 20));
    unsigned short* QThi = (unsigned short*)(ws + ( 8u << 20));
    unsigned short* QTlo = (unsigned short*)(ws + (12u << 20));
    unsigned short* Vc   = (unsigned short*)(ws + (16u << 20));
    float*          R32  = (float*)         (ws + (20u << 20));   // 8 MB -> ends at 28 MB

    const size_t base = (size_t)28u << 20;
    int nsplit = 3;   // grid 768 = exactly 3 blocks/CU, no occupancy tail
    {
        size_t nblk = (size_t)256 * 3;
        size_t need = base + nblk * 8192 * 4 + 2 * nblk * 128 * 4;
        if (ws_size < need) nsplit = 1;
    }
    const size_t nblk = (size_t)256 * nsplit;
    float* Pacc = (float*)(ws + base);
    float* Mp   = (float*)(ws + base + nblk * 8192 * 4);
    float* Lp   = (float*)(ws + base + nblk * 8192 * 4 + nblk * 128 * 4);

    conv_prep<<<dim3(1024), dim3(256), 0, stream>>>(
        xlow, xhigh, Wl, bl, Wh, bh, KThi, KTlo, QThi, QTlo, Vc, R32);
    attn_fused<<<dim3((unsigned)nblk), dim3(256), 0, stream>>>(
        KThi, KTlo, QThi, QTlo, Vc, Pacc, Mp, Lp, nsplit);
    attn_combine<<<dim3(1024), dim3(256), 0, stream>>>(
        Pacc, Mp, Lp, R32, (float*)d_out, nsplit);
}

// Round 5
// 135.233 us; speedup vs baseline: 3.7625x; 1.1802x over previous
//
#include <hip/hip_runtime.h>
#include <hip/hip_bf16.h>
#include <stdint.h>

#define BATCH 8
#define NPOS 4096   // H*W = 64*64
#define LOG2E 1.4426950408889634f
#define THR_LOG2 11.54f   // defer-max threshold (8 nats in log2 units)

typedef __attribute__((ext_vector_type(4)))  float f32x4;
typedef __attribute__((ext_vector_type(16))) float f32x16;
typedef __attribute__((ext_vector_type(8)))  short bf16x8;

__device__ __forceinline__ unsigned short bf_rne(float f) {
    unsigned u = __float_as_uint(f);
    u += 0x7fffu + ((u >> 16) & 1u);
    return (unsigned short)(u >> 16);
}
__device__ __forceinline__ unsigned cvt_pk_bf16(float lo, float hi) {
    unsigned r;
    asm("v_cvt_pk_bf16_f32 %0, %1, %2" : "=v"(r) : "v"(lo), "v"(hi));
    return r;
}
// a' = [a_lo | b_lo-from-partner], b' = [a_hi-from-partner | b_hi]
__device__ __forceinline__ void permswap32(unsigned &a, unsigned &b) {
    asm volatile("v_permlane32_swap_b32 %0, %1" : "+v"(a), "+v"(b));
}

// ---------------------------------------------------------------------------
// Kernel 1: both 1x1 convs. Block = (b, nb, pass), 256 threads = 4 waves;
// wave w = channel-quarter (W/bias reads wave-uniform -> s_load).
// x panel staged once in LDS (16KB), shared by 4 waves.
//   KThi [B][N][64] bf16 (A, transposed)           -> K operand
//   QThi [B][N][64] bf16 (Bf * log2e, transposed)  -> Q operand (log2 domain)
//   Vc   [B][64][N] bf16 (Bf)                      -> V operand
//   R32  [B][64][N] f32  (Bf)                      -> residual
// ---------------------------------------------------------------------------
__global__ __launch_bounds__(256)
void conv_prep(const float* __restrict__ xlow, const float* __restrict__ xhigh,
               const float* __restrict__ Wl, const float* __restrict__ bl,
               const float* __restrict__ Wh, const float* __restrict__ bh,
               unsigned short* __restrict__ KThi, unsigned short* __restrict__ QThi,
               unsigned short* __restrict__ Vc, float* __restrict__ R32)
{
    const int id   = blockIdx.x;
    const int b    = id & 7;
    const int rest = id >> 3;
    const int nb   = rest & 63;
    const int pass = rest >> 6;       // 0 = low (K), 1 = high (Q/V/R)
    const int t    = threadIdx.x;
    const int pos  = t & 63;
    const int oq   = t >> 6;
    const int n    = nb * 64 + pos;
    const int o0   = oq * 16;

    const float* __restrict__ x    = pass ? xhigh : xlow;
    const float* __restrict__ W    = pass ? Wh : Wl;
    const float* __restrict__ bias = pass ? bh : bl;

    __shared__ float xs[64][65];

    {   // stage x panel: thread t loads ch = t>>2, 16 consecutive floats
        const int ch = t >> 2, seg = t & 3;
        const float* sp = x + ((size_t)(b * 64 + ch)) * NPOS + nb * 64 + seg * 16;
#pragma unroll
        for (int q = 0; q < 4; ++q) {
            f32x4 v = *(const f32x4*)(sp + q * 4);
#pragma unroll
            for (int e = 0; e < 4; ++e)
                xs[seg * 16 + q * 4 + e][ch] = v[e];
        }
    }
    __syncthreads();

    float xr[64];
#pragma unroll
    for (int i = 0; i < 16; ++i) {
        f32x4 v = *(const f32x4*)&xs[pos][i * 4];
#pragma unroll
        for (int e = 0; e < 4; ++e) xr[i * 4 + e] = v[e];
    }

    unsigned hpack[8];
#pragma unroll
    for (int oo = 0; oo < 16; ++oo) {
        const int o = o0 + oo;
        float acc = bias[o];
#pragma unroll
        for (int i = 0; i < 64; ++i)
            acc = fmaf(W[o * 64 + i], xr[i], acc);

        if (pass) {
            Vc [((size_t)(b * 64 + o)) * NPOS + n] = bf_rne(acc);
            R32[((size_t)(b * 64 + o)) * NPOS + n] = acc;
        }
        // Q is pre-scaled by log2e so softmax runs in pure log2 domain
        unsigned short h = bf_rne(pass ? acc * LOG2E : acc);
        if (oo & 1) hpack[oo >> 1] |= ((unsigned)h) << 16;
        else        hpack[oo >> 1]  = h;
    }

    unsigned short* dh = pass ? QThi : KThi;
    uint4* ph = (uint4*)(dh + ((size_t)(b * NPOS + n)) * 64 + o0);
#pragma unroll
    for (int q = 0; q < 2; ++q) {
        uint4 v; v.x = hpack[4*q]; v.y = hpack[4*q+1]; v.z = hpack[4*q+2]; v.w = hpack[4*q+3];
        ph[q] = v;
    }
}

// ---------------------------------------------------------------------------
// LDS staging of one 64-key supertile (16 KB):
//   [0,4K) Khi(it=0)  [4K,8K) Khi(it=1)  [8K,16K) V
// K tiles: [32 keys][128B rows]; V: [64 ch][128B rows].
// XOR swizzle chunk^=(row&7) applied on the GLOBAL source (rule #21).
// ---------------------------------------------------------------------------
__device__ __forceinline__ void stage_st(const unsigned short* __restrict__ KThi,
                                         const unsigned short* __restrict__ Vc,
                                         int b, int j0, char* dst, int w, int lane)
{
#pragma unroll
    for (int q = 0; q < 4; ++q) {
        const int S = w * 4 + q;               // 0..15, wave-uniform
        const unsigned short* src;
        if (S < 8) {
            const int it  = S >> 2;
            const int E   = ((S & 3) << 6) | lane;
            const int row = E >> 3, c = E & 7;
            src = KThi + ((size_t)b * NPOS + j0 + it * 32 + row) * 64 + ((c ^ (row & 7)) << 3);
        } else {
            const int E   = ((S - 8) << 6) | lane;
            const int row = E >> 3, c = E & 7;
            src = Vc + ((size_t)(b * 64 + row)) * NPOS + j0 + ((c ^ (row & 7)) << 3);
        }
        __builtin_amdgcn_global_load_lds(
            (const __attribute__((address_space(1))) unsigned int*)(const void*)src,
            (__attribute__((address_space(3))) unsigned int*)(void*)(dst + S * 1024),
            16, 0, 0);
    }
}

// ---------------------------------------------------------------------------
// Kernel 2: flash attention partials. 4 waves x 32 q-rows = 128 q/block.
// mfma_f32_32x32x16_bf16, swapped operands (lane owns ONE q-row).
// Plain-bf16 QK^T (logit noise sigma ~0.006 -> negligible vs threshold).
// 2x16KB double-buffered LDS -> 4 blocks/CU.
// ---------------------------------------------------------------------------
__global__ __launch_bounds__(256, 4)
void attn_fused(const unsigned short* __restrict__ KThi,
                const unsigned short* __restrict__ QThi,
                const unsigned short* __restrict__ Vc,
                float* __restrict__ Pacc, float* __restrict__ Mp, float* __restrict__ Lp,
                int nsplit)
{
    const int id   = blockIdx.x;
    const int b    = id & 7;            // one batch per XCD
    const int qb   = (id >> 3) & 31;    // q-tile (128 rows)
    const int s    = id >> 8;           // KV split index
    const int tid  = threadIdx.x;
    const int w    = tid >> 6;
    const int lane = tid & 63;
    const int r31  = lane & 31;
    const int g2   = lane >> 5;

    const int st0 = (64 * s) / nsplit;
    const int nst = (64 * (s + 1)) / nsplit - st0;

    __shared__ __align__(1024) char smem[32768];   // 2 x 16KB supertile buffers

    // Q fragments hoisted (B-operand: col=lane&31=q, k=(lane>>5)*8+e)
    const int qrow = qb * 128 + w * 32 + r31;
    bf16x8 qhi[4];
#pragma unroll
    for (int kk = 0; kk < 4; ++kk)
        qhi[kk] = *(const bf16x8*)(QThi + ((size_t)b * NPOS + qrow) * 64 + kk * 16 + g2 * 8);

    f32x16 accO0, accO1;
#pragma unroll
    for (int r = 0; r < 16; ++r) { accO0[r] = 0.f; accO1[r] = 0.f; }
    float m_run = -1e30f, l_run = 0.f;

    stage_st(KThi, Vc, b, st0 * 64, smem, w, lane);
    __syncthreads();

    for (int st = 0; st < nst; ++st) {
        char* buf = smem + (st & 1) * 16384;
        if (st + 1 < nst)
            stage_st(KThi, Vc, b, (st0 + st + 1) * 64, smem + ((st + 1) & 1) * 16384, w, lane);

#pragma unroll
        for (int it = 0; it < 2; ++it) {
            // ---- QK^T (plain bf16, log2-domain logits) ----
            f32x16 sA;
#pragma unroll
            for (int r = 0; r < 16; ++r) sA[r] = 0.f;
            const char* Kb = buf + it * 4096;
            __builtin_amdgcn_s_setprio(1);
#pragma unroll
            for (int kk = 0; kk < 4; ++kk) {
                const int cb  = (kk << 1) | g2;
                const int off = r31 * 128 + ((cb ^ (r31 & 7)) << 4);
                bf16x8 kh = *(const bf16x8*)(Kb + off);
                sA = __builtin_amdgcn_mfma_f32_32x32x16_bf16(kh, qhi[kk], sA, 0, 0, 0);
            }
            __builtin_amdgcn_s_setprio(0);

            // ---- online softmax (balanced max tree; partner half via lane^32) ----
            float t01 = fmaxf(sA[0], sA[1]),   t23 = fmaxf(sA[2], sA[3]);
            float t45 = fmaxf(sA[4], sA[5]),   t67 = fmaxf(sA[6], sA[7]);
            float t89 = fmaxf(sA[8], sA[9]),   tab = fmaxf(sA[10], sA[11]);
            float tcd = fmaxf(sA[12], sA[13]), tef = fmaxf(sA[14], sA[15]);
            float q0 = fmaxf(fmaxf(t01, t23), fmaxf(t45, t67));
            float q1 = fmaxf(fmaxf(t89, tab), fmaxf(tcd, tef));
            float tmax = fmaxf(q0, q1);
            tmax = fmaxf(tmax, __shfl_xor(tmax, 32, 64));

            // defer-max (T13): rescale only when the running max really grows
            if (!__all(tmax <= m_run + THR_LOG2)) {
                const float nm = fmaxf(m_run, tmax);
                const float sc = exp2f(m_run - nm);
                m_run = nm;
                l_run *= sc;
#pragma unroll
                for (int r = 0; r < 16; ++r) { accO0[r] *= sc; accO1[r] *= sc; }
            }

            float p[16];
            float ps = 0.f;
#pragma unroll
            for (int r = 0; r < 16; ++r) {
                p[r] = exp2f(sA[r] - m_run);
                ps += p[r];
            }
            ps += __shfl_xor(ps, 32, 64);
            l_run += ps;

            // ---- P -> bf16 B-frags in-register (cvt_pk + permlane32_swap) ----
            unsigned wpk[8];
#pragma unroll
            for (int h = 0; h < 8; ++h)
                wpk[h] = cvt_pk_bf16(p[2*h], p[2*h+1]);
            unsigned a0 = wpk[0], b0 = wpk[2]; permswap32(a0, b0);
            unsigned a1 = wpk[1], b1 = wpk[3]; permswap32(a1, b1);
            unsigned a2 = wpk[4], b2 = wpk[6]; permswap32(a2, b2);
            unsigned a3 = wpk[5], b3 = wpk[7]; permswap32(a3, b3);
            union { unsigned u[4]; bf16x8 v; } fa0, fa1;
            fa0.u[0] = a0; fa0.u[1] = a1; fa0.u[2] = b0; fa0.u[3] = b1;
            fa1.u[0] = a2; fa1.u[1] = a3; fa1.u[2] = b2; fa1.u[3] = b3;

            // ---- PV: O^T += V^T · P ----
            __builtin_amdgcn_s_setprio(1);
            {   // channels 0..31
                const int ch = r31;
                const int c0 = (((it * 2 + 0) << 1) | g2) ^ (ch & 7);
                const int c1 = (((it * 2 + 1) << 1) | g2) ^ (ch & 7);
                bf16x8 vf0 = *(const bf16x8*)(buf + 8192 + ch * 128 + (c0 << 4));
                bf16x8 vf1 = *(const bf16x8*)(buf + 8192 + ch * 128 + (c1 << 4));
                accO0 = __builtin_amdgcn_mfma_f32_32x32x16_bf16(vf0, fa0.v, accO0, 0, 0, 0);
                accO0 = __builtin_amdgcn_mfma_f32_32x32x16_bf16(vf1, fa1.v, accO0, 0, 0, 0);
            }
            {   // channels 32..63
                const int ch = 32 + r31;
                const int c0 = (((it * 2 + 0) << 1) | g2) ^ (ch & 7);
                const int c1 = (((it * 2 + 1) << 1) | g2) ^ (ch & 7);
                bf16x8 vf0 = *(const bf16x8*)(buf + 8192 + ch * 128 + (c0 << 4));
                bf16x8 vf1 = *(const bf16x8*)(buf + 8192 + ch * 128 + (c1 << 4));
                accO1 = __builtin_amdgcn_mfma_f32_32x32x16_bf16(vf0, fa0.v, accO1, 0, 0, 0);
                accO1 = __builtin_amdgcn_mfma_f32_32x32x16_bf16(vf1, fa1.v, accO1, 0, 0, 0);
            }
            __builtin_amdgcn_s_setprio(0);
        }
        __syncthreads();   // drains vmcnt (stage st+1 done) + all LDS reads of buf
    }

    // ---- epilogue: unnormalized partials, O^T layout [64 d][128 q] ----
#pragma unroll
    for (int r = 0; r < 16; ++r) {
        const int d0 = (r & 3) + 8 * (r >> 2) + 4 * g2;
        Pacc[(size_t)id * 8192 + (size_t)d0 * 128 + w * 32 + r31]        = accO0[r];
        Pacc[(size_t)id * 8192 + (size_t)(d0 + 32) * 128 + w * 32 + r31] = accO1[r];
    }
    if (g2 == 0) {
        Mp[(size_t)id * 128 + w * 32 + r31] = m_run;
        Lp[(size_t)id * 128 + w * 32 + r31] = l_run;
    }
}

// ---------------------------------------------------------------------------
// Kernel 3: combine partials across splits + residual add (log2 domain).
// ---------------------------------------------------------------------------
__global__ __launch_bounds__(256)
void attn_combine(const float* __restrict__ Pacc, const float* __restrict__ Mp,
                  const float* __restrict__ Lp, const float* __restrict__ R32,
                  float* __restrict__ out, int nsplit)
{
    const int cid     = blockIdx.x;
    const int quarter = cid & 3;
    const int b       = (cid >> 2) & 7;
    const int qb      = cid >> 5;        // 0..31
    const int t       = threadIdx.x;

    __shared__ float wgt[4][128];
    __shared__ float invL[128];

    if (t < 128) {
        float m = -1e30f;
        for (int s = 0; s < nsplit; ++s)
            m = fmaxf(m, Mp[(size_t)((s << 8) | (qb << 3) | b) * 128 + t]);
        float L = 0.f;
        for (int s = 0; s < nsplit; ++s) {
            const size_t p = (size_t)((s << 8) | (qb << 3) | b);
            float wv = exp2f(Mp[p * 128 + t] - m);
            wgt[s][t] = wv;
            L += wv * Lp[p * 128 + t];
        }
        invL[t] = 1.0f / L;
    }
    __syncthreads();

    const int c_loc = t >> 4;
    const int c     = quarter * 16 + c_loc;
    const int q0    = (t & 15) * 8;
    const size_t obase = ((size_t)(b * 64 + c)) * NPOS + qb * 128 + q0;

#pragma unroll
    for (int hv = 0; hv < 2; ++hv) {
        const int q = q0 + hv * 4;
        f32x4 acc = (f32x4){0.f, 0.f, 0.f, 0.f};
        for (int s = 0; s < nsplit; ++s) {
            const size_t p = (size_t)((s << 8) | (qb << 3) | b);
            f32x4 pa = *(const f32x4*)(Pacc + p * 8192 + (size_t)c * 128 + q);
#pragma unroll
            for (int e = 0; e < 4; ++e)
                acc[e] += wgt[s][q + e] * pa[e];
        }
        f32x4 rv = *(const f32x4*)(R32 + obase + hv * 4);
        f32x4 v;
#pragma unroll
        for (int e = 0; e < 4; ++e)
            v[e] = acc[e] * invL[q + e] + rv[e];
        *(f32x4*)(out + obase + hv * 4) = v;
    }
}

// ---------------------------------------------------------------------------
extern "C" void kernel_launch(void* const* d_in, const int* in_sizes, int n_in,
                              void* d_out, int out_size, void* d_ws, size_t ws_size,
                              hipStream_t stream)
{
    const float* xlow  = (const float*)d_in[0];
    const float* xhigh = (const float*)d_in[1];
    const float* Wl    = (const float*)d_in[2];
    const float* bl    = (const float*)d_in[3];
    const float* Wh    = (const float*)d_in[4];
    const float* bh    = (const float*)d_in[5];

    char* ws = (char*)d_ws;
    unsigned short* KThi = (unsigned short*)(ws);                  // 4 MB
    unsigned short* QThi = (unsigned short*)(ws + ( 4u << 20));    // 4 MB
    unsigned short* Vc   = (unsigned short*)(ws + ( 8u << 20));    // 4 MB
    float*          R32  = (float*)         (ws + (12u << 20));    // 8 MB -> 20 MB

    const size_t base = (size_t)20u << 20;
    int nsplit = 4;   // 1024 blocks = exactly 4 blocks/CU
    while (nsplit > 1) {
        size_t nblk = (size_t)256 * nsplit;
        size_t need = base + nblk * 8192 * 4 + 2 * nblk * 128 * 4;
        if (need <= ws_size) break;
        --nsplit;
    }
    const size_t nblk = (size_t)256 * nsplit;
    float* Pacc = (float*)(ws + base);
    float* Mp   = (float*)(ws + base + nblk * 8192 * 4);
    float* Lp   = (float*)(ws + base + nblk * 8192 * 4 + nblk * 128 * 4);

    conv_prep<<<dim3(1024), dim3(256), 0, stream>>>(
        xlow, xhigh, Wl, bl, Wh, bh, KThi, QThi, Vc, R32);
    attn_fused<<<dim3((unsigned)nblk), dim3(256), 0, stream>>>(
        KThi, QThi, Vc, Pacc, Mp, Lp, nsplit);
    attn_combine<<<dim3(1024), dim3(256), 0, stream>>>(
        Pacc, Mp, Lp, R32, (float*)d_out, nsplit);
}